// Round 10
// baseline (7832.368 us; speedup 1.0000x reference)
//
#include <hip/hip_runtime.h>

// SimpleEdgeModel round 10: ZERO-LDS edge kernel via the K=16 identity.
//
// R8/R9 lesson: the C->B-frag LDS handoff for 16x16x32 layer 3 is
// uncontrollable from source (2 corruption rounds).  Replacement: 16x16x16
// MFMA's B-frag is B[k=4q+e][n=c] — exactly the 4-contiguous rows that the
// layer-2 C-layout (row=16nt+4q+r, col=c) already delivers.  So the packed
// f16x4 pk[nt][jt] = relu(acc2+bc2) IS the layer-3 B operand: no LDS, no
// fences, no transpose.  W3 pre-packed as K16 A-frags (W3^T).
// jt=2 per wave (reg safety: e1 32 + pk 32 + acc 8 + wf 8 ~ 95 peak << 128),
// grid 4096 blocks, LDS 0 -> occupancy VGPR-bound (~20 waves/CU).
//
// out[b,i,j] = Wo.relu(W3^T.relu(W2^T.relu(g_j+bc1-g_i)+bc2)+bc3)+bo
// g = nodeMLP(x)@Wc1 (layer c1 linear -> folded per node).

typedef _Float16 half_t;
typedef __attribute__((ext_vector_type(4))) _Float16 f16x4;
typedef __attribute__((ext_vector_type(8))) _Float16 f16x8;
typedef __attribute__((ext_vector_type(4))) float f32x4;

// ws layout:
//   gh  : 1024*128 f16 @ 0        = f16(g)
//   gbh : 1024*128 f16 @ 262144   = f16(g + bc1)
//   W2T : 16384 f16    @ 524288   (frag-packed Wc2, 16x16x32 A-operand order)
//   W3T : 16384 f16    @ 557056   (frag-packed Wc3, 16x16x16 A-operand order)

// ---------------------------------------------------------------------------
// prep: blocks 0..255 node MLP (4 nodes/block, verbatim since R6);
//       blocks 256..263: W2 pack, frag (ks,nt): elem L*8+e <- Wc2[32ks+8q+e][16nt+c]
//       blocks 264..271: W3 pack, frag (kc,nt3): elem L*4+e <- Wc3[16kc+4q+e][16nt3+c]
// ---------------------------------------------------------------------------
__global__ __launch_bounds__(256) void prep_kernel(
    const float* __restrict__ x, const float* __restrict__ Wa, const float* __restrict__ ba,
    const float* __restrict__ Wb, const float* __restrict__ bb, const float* __restrict__ Wc1,
    const float* __restrict__ bc1, const float* __restrict__ Wc2, const float* __restrict__ Wc3,
    half_t* __restrict__ gh, half_t* __restrict__ gbh,
    half_t* __restrict__ W2T, half_t* __restrict__ W3T)
{
  const int t = threadIdx.x;
  if (blockIdx.x >= 264) {                       // W3 -> K16 A-frags
    const int nt3 = blockIdx.x - 264;
    const int kc = t >> 5, sub = t & 31;
    #pragma unroll
    for (int l = 0; l < 2; l++) {
      const int L = sub * 2 + l, q = L >> 4, cc = L & 15;
      f16x4 v;
      #pragma unroll
      for (int e = 0; e < 4; e++)
        v[e] = (half_t)Wc3[(16 * kc + 4 * q + e) * 128 + 16 * nt3 + cc];
      *(f16x4*)(W3T + (kc * 8 + nt3) * 256 + L * 4) = v;
    }
    return;
  }
  if (blockIdx.x >= 256) {                       // W2 -> K32 A-frags
    const int nt = blockIdx.x - 256;
    const int ks = t >> 6, L = t & 63, q = L >> 4, cc = L & 15;
    f16x8 v;
    #pragma unroll
    for (int e = 0; e < 8; e++)
      v[e] = (half_t)Wc2[(32 * ks + 8 * q + e) * 128 + 16 * nt + cc];
    *(f16x8*)(W2T + (ks * 8 + nt) * 512 + L * 8) = v;
    return;
  }
  __shared__ float sx[64 * 6];
  __shared__ float sh1[128 * 6];
  __shared__ float sh2[128 * 6];
  const int n0 = blockIdx.x * 4;
  const int col = t & 127, hf = t >> 7;

  sx[(t & 63) * 6 + (t >> 6)] = x[(n0 + (t >> 6)) * 64 + (t & 63)];
  __syncthreads();

  float a0 = ba[col], a1 = a0;
  #pragma unroll
  for (int cc = 0; cc < 64; cc++) {
    const float wv = Wa[cc * 128 + col];
    const float2 xv = *(const float2*)(sx + cc * 6 + hf * 2);
    a0 = fmaf(xv.x, wv, a0); a1 = fmaf(xv.y, wv, a1);
  }
  *(float2*)(sh1 + col * 6 + hf * 2) = make_float2(fmaxf(a0, 0.f), fmaxf(a1, 0.f));
  __syncthreads();

  float b0 = bb[col], b1 = b0;
  #pragma unroll
  for (int k = 0; k < 128; k++) {
    const float wv = Wb[k * 128 + col];
    const float2 hv = *(const float2*)(sh1 + k * 6 + hf * 2);
    b0 = fmaf(hv.x, wv, b0); b1 = fmaf(hv.y, wv, b1);
  }
  *(float2*)(sh2 + col * 6 + hf * 2) = make_float2(fmaxf(b0, 0.f), fmaxf(b1, 0.f));
  __syncthreads();

  float c0 = 0.f, c1 = 0.f;
  #pragma unroll
  for (int k = 0; k < 128; k++) {
    const float wv = Wc1[k * 128 + col];
    const float2 hv = *(const float2*)(sh2 + k * 6 + hf * 2);
    c0 = fmaf(hv.x, wv, c0); c1 = fmaf(hv.y, wv, c1);
  }
  const float bv = bc1[col];
  const int r0 = n0 + hf * 2;
  gh [(r0 + 0) * 128 + col] = (half_t)c0;
  gh [(r0 + 1) * 128 + col] = (half_t)c1;
  gbh[(r0 + 0) * 128 + col] = (half_t)(c0 + bv);
  gbh[(r0 + 1) * 128 + col] = (half_t)(c1 + bv);
}

// ---------------------------------------------------------------------------
// edge kernel. 4096 blocks = b(1b) x jgroup(2b, 128 j each) x i(9b).
// Wave w owns j-rows [jg*128 + w*32, +32) as 2 16-row tiles.  NO LDS.
// ---------------------------------------------------------------------------
static __device__ inline f16x8 relu_sub8(f16x8 a, f16x8 b) {
  f16x8 d = a - b;
  const f16x8 z = {};
  return __builtin_elementwise_max(d, z);
}

__global__ __launch_bounds__(256)
void edge_kernel(
    const half_t* __restrict__ gh, const half_t* __restrict__ gbh,
    const half_t* __restrict__ W2T, const half_t* __restrict__ W3T,
    const float* __restrict__ bc2, const float* __restrict__ bc3,
    const float* __restrict__ Wo, const float* __restrict__ bo,
    float* __restrict__ out)
{
  const int t = threadIdx.x, lane = t & 63, w = t >> 6;
  const int c = lane & 15, q = lane >> 4;
  const int bid = blockIdx.x;
  const int b = bid >> 11, jg = (bid >> 9) & 3, i = bid & 511;
  const int j0w = jg * 128 + w * 32;
  const float bo0 = bo[0];
  const int rdoff = lane * 8;

  // ---- phase A: e1[ks][jt] in regs (32 VGPRs) ----
  f16x8 e1[4][2];
  {
    f16x8 gih[4];
    #pragma unroll
    for (int ks = 0; ks < 4; ks++)
      gih[ks] = *(const f16x8*)(gh + (size_t)(b * 512 + i) * 128 + ks * 32 + q * 8);
    #pragma unroll
    for (int ks = 0; ks < 4; ks++)
      #pragma unroll
      for (int jt = 0; jt < 2; jt++) {
        const f16x8 gj = *(const f16x8*)(gbh + (size_t)(b * 512 + j0w + jt * 16 + c) * 128 + ks * 32 + q * 8);
        e1[ks][jt] = relu_sub8(gj, gih[ks]);
      }
  }

  // ---- phase B: layer 2 (16x16x32); pk[nt][jt] = relu(acc2+bc2) packed
  //      f16x4 — identical bits to the layer-3 16x16x16 B-fragment ----
  f16x4 pk[8][2];
  #pragma unroll 1
  for (int nt = 0; nt < 8; nt++) {
    f32x4 acc[2] = {};
    #pragma unroll 1
    for (int ks = 0; ks < 4; ks++) {
      const f16x8 wf = *(const f16x8*)(W2T + (ks * 8 + nt) * 512 + rdoff);
      #pragma unroll
      for (int jt = 0; jt < 2; jt++)
        acc[jt] = __builtin_amdgcn_mfma_f32_16x16x32_f16(wf, e1[ks][jt], acc[jt], 0, 0, 0);
    }
    const f32x4 b2 = *(const f32x4*)(bc2 + nt * 16 + q * 4);
    #pragma unroll
    for (int jt = 0; jt < 2; jt++) {
      f16x4 pv;
      pv[0] = (half_t)fmaxf(acc[jt][0] + b2[0], 0.f);
      pv[1] = (half_t)fmaxf(acc[jt][1] + b2[1], 0.f);
      pv[2] = (half_t)fmaxf(acc[jt][2] + b2[2], 0.f);
      pv[3] = (half_t)fmaxf(acc[jt][3] + b2[3], 0.f);
      pk[nt][jt] = pv;
    }
  }

  // ---- phase C: layer 3 (16x16x16, kc = layer-2 nt), epilogue fused ----
  float p[2] = {0.f, 0.f};
  #pragma unroll 1
  for (int nt3 = 0; nt3 < 8; nt3++) {
    f32x4 acc[2] = {};
    #pragma unroll 1
    for (int kc = 0; kc < 8; kc++) {
      const f16x4 wf = *(const f16x4*)(W3T + (kc * 8 + nt3) * 256 + lane * 4);
      #pragma unroll
      for (int jt = 0; jt < 2; jt++)
        acc[jt] = __builtin_amdgcn_mfma_f32_16x16x16f16(wf, pk[kc][jt], acc[jt], 0, 0, 0);
    }
    const f32x4 b3 = *(const f32x4*)(bc3 + nt3 * 16 + q * 4);
    const f32x4 wo = *(const f32x4*)(Wo  + nt3 * 16 + q * 4);
    #pragma unroll
    for (int jt = 0; jt < 2; jt++)
      #pragma unroll
      for (int r = 0; r < 4; r++)
        p[jt] = fmaf(fmaxf(acc[jt][r] + b3[r], 0.f), wo[r], p[jt]);
  }

  // ---- reduce over q (n3 rows split across q), store ----
  #pragma unroll
  for (int jt = 0; jt < 2; jt++) {
    p[jt] += __shfl_xor(p[jt], 16, 64);
    p[jt] += __shfl_xor(p[jt], 32, 64);
  }
  if (q == 0) {
    const size_t base = ((size_t)(b * 512 + i)) * 512 + j0w;
    out[base + c]      = p[0] + bo0;
    out[base + 16 + c] = p[1] + bo0;
  }
}

// ---------------------------------------------------------------------------
extern "C" void kernel_launch(void* const* d_in, const int* in_sizes, int n_in,
                              void* d_out, int out_size, void* d_ws, size_t ws_size,
                              hipStream_t stream)
{
  const float* x   = (const float*)d_in[0];
  const float* Wa  = (const float*)d_in[1];
  const float* ba  = (const float*)d_in[2];
  const float* Wb  = (const float*)d_in[3];
  const float* bb  = (const float*)d_in[4];
  const float* Wc1 = (const float*)d_in[5];
  const float* bc1 = (const float*)d_in[6];
  const float* Wc2 = (const float*)d_in[7];
  const float* bc2 = (const float*)d_in[8];
  const float* Wc3 = (const float*)d_in[9];
  const float* bc3 = (const float*)d_in[10];
  const float* Wo  = (const float*)d_in[11];
  const float* bo  = (const float*)d_in[12];
  float* out = (float*)d_out;

  char* ws = (char*)d_ws;
  half_t* gh  = (half_t*)ws;                      // 256 KB
  half_t* gbh = (half_t*)(ws + 262144);           // 256 KB
  half_t* W2T = (half_t*)(ws + 524288);           // 32 KB
  half_t* W3T = (half_t*)(ws + 557056);           // 32 KB

  prep_kernel<<<272, 256, 0, stream>>>(x, Wa, ba, Wb, bb, Wc1, bc1, Wc2, Wc3,
                                       gh, gbh, W2T, W3T);
  edge_kernel<<<4096, 256, 0, stream>>>(gh, gbh, W2T, W3T, bc2, bc3, Wo, bo, out);
}

// Round 11
// 3734.355 us; speedup vs baseline: 2.0974x; 2.0974x over previous
//
#include <hip/hip_runtime.h>

// SimpleEdgeModel round 11: R10's zero-LDS-dataflow K16-identity kernel +
// a 40 KB dummy LDS allocation to steer the register allocator.
//
// R10 post-mortem: with LDS=0 the backend targets 8 waves/EU -> ~64-VGPR
// budget -> e1/pk spilled to scratch in the inner loops (VGPR_Count 68,
// MfmaUtil 0.25%, 7.8 ms).  Allocator model (fits R2..R10): budget =
// 512 / (waves-per-EU permitted by LDS), capped at 128.  So: allocate 40 KB
// LDS (4 blocks/CU -> 4 waves/EU -> budget 128; demand ~99 -> no spills),
// guarded by a runtime-unprovable branch so it can't be eliminated.
// Also: W3 frags packed in kc-pairs -> layer-3 weight loads are b128.
//
// out[b,i,j] = Wo.relu(W3^T.relu(W2^T.relu(g_j+bc1-g_i)+bc2)+bc3)+bo
// g = nodeMLP(x)@Wc1 (layer c1 linear -> folded per node).
// K16 identity: 16x16x16 B-frag is B[k=4q+e][n=c] == layer-2 C-layout rows,
// so pk[nt][jt]=relu(acc2+bc2) feeds layer 3 with zero data movement.

typedef _Float16 half_t;
typedef __attribute__((ext_vector_type(4))) _Float16 f16x4;
typedef __attribute__((ext_vector_type(8))) _Float16 f16x8;
typedef __attribute__((ext_vector_type(4))) float f32x4;

// ws layout:
//   gh  : 1024*128 f16 @ 0        = f16(g)
//   gbh : 1024*128 f16 @ 262144   = f16(g + bc1)
//   W2T : 16384 f16    @ 524288   (frag-packed Wc2, 16x16x32 A-operand order)
//   W3T : 16384 f16    @ 557056   (frag-packed Wc3, K16 A-frags, kc-paired)

// ---------------------------------------------------------------------------
// prep: blocks 0..255 node MLP (verbatim since R6);
//   256..263: W2 pack, frag (ks,nt): elem L*8+e <- Wc2[32ks+8q+e][16nt+c]
//   264..271: W3 pack, kc-paired: half index
//     ((kc>>1)*8+nt3)*512 + L*8 + (kc&1)*4 + e <- Wc3[16kc+4q+e][16nt3+c]
// ---------------------------------------------------------------------------
__global__ __launch_bounds__(256) void prep_kernel(
    const float* __restrict__ x, const float* __restrict__ Wa, const float* __restrict__ ba,
    const float* __restrict__ Wb, const float* __restrict__ bb, const float* __restrict__ Wc1,
    const float* __restrict__ bc1, const float* __restrict__ Wc2, const float* __restrict__ Wc3,
    half_t* __restrict__ gh, half_t* __restrict__ gbh,
    half_t* __restrict__ W2T, half_t* __restrict__ W3T)
{
  const int t = threadIdx.x;
  if (blockIdx.x >= 264) {                       // W3 -> K16 A-frags (kc-paired)
    const int nt3 = blockIdx.x - 264;
    const int kc = t >> 5, sub = t & 31;
    #pragma unroll
    for (int l = 0; l < 2; l++) {
      const int L = sub * 2 + l, q = L >> 4, cc = L & 15;
      f16x4 v;
      #pragma unroll
      for (int e = 0; e < 4; e++)
        v[e] = (half_t)Wc3[(16 * kc + 4 * q + e) * 128 + 16 * nt3 + cc];
      *(f16x4*)(W3T + ((kc >> 1) * 8 + nt3) * 512 + L * 8 + (kc & 1) * 4) = v;
    }
    return;
  }
  if (blockIdx.x >= 256) {                       // W2 -> K32 A-frags
    const int nt = blockIdx.x - 256;
    const int ks = t >> 6, L = t & 63, q = L >> 4, cc = L & 15;
    f16x8 v;
    #pragma unroll
    for (int e = 0; e < 8; e++)
      v[e] = (half_t)Wc2[(32 * ks + 8 * q + e) * 128 + 16 * nt + cc];
    *(f16x8*)(W2T + (ks * 8 + nt) * 512 + L * 8) = v;
    return;
  }
  __shared__ float sx[64 * 6];
  __shared__ float sh1[128 * 6];
  __shared__ float sh2[128 * 6];
  const int n0 = blockIdx.x * 4;
  const int col = t & 127, hf = t >> 7;

  sx[(t & 63) * 6 + (t >> 6)] = x[(n0 + (t >> 6)) * 64 + (t & 63)];
  __syncthreads();

  float a0 = ba[col], a1 = a0;
  #pragma unroll
  for (int cc = 0; cc < 64; cc++) {
    const float wv = Wa[cc * 128 + col];
    const float2 xv = *(const float2*)(sx + cc * 6 + hf * 2);
    a0 = fmaf(xv.x, wv, a0); a1 = fmaf(xv.y, wv, a1);
  }
  *(float2*)(sh1 + col * 6 + hf * 2) = make_float2(fmaxf(a0, 0.f), fmaxf(a1, 0.f));
  __syncthreads();

  float b0 = bb[col], b1 = b0;
  #pragma unroll
  for (int k = 0; k < 128; k++) {
    const float wv = Wb[k * 128 + col];
    const float2 hv = *(const float2*)(sh1 + k * 6 + hf * 2);
    b0 = fmaf(hv.x, wv, b0); b1 = fmaf(hv.y, wv, b1);
  }
  *(float2*)(sh2 + col * 6 + hf * 2) = make_float2(fmaxf(b0, 0.f), fmaxf(b1, 0.f));
  __syncthreads();

  float c0 = 0.f, c1 = 0.f;
  #pragma unroll
  for (int k = 0; k < 128; k++) {
    const float wv = Wc1[k * 128 + col];
    const float2 hv = *(const float2*)(sh2 + k * 6 + hf * 2);
    c0 = fmaf(hv.x, wv, c0); c1 = fmaf(hv.y, wv, c1);
  }
  const float bv = bc1[col];
  const int r0 = n0 + hf * 2;
  gh [(r0 + 0) * 128 + col] = (half_t)c0;
  gh [(r0 + 1) * 128 + col] = (half_t)c1;
  gbh[(r0 + 0) * 128 + col] = (half_t)(c0 + bv);
  gbh[(r0 + 1) * 128 + col] = (half_t)(c1 + bv);
}

// ---------------------------------------------------------------------------
// edge kernel. 4096 blocks = b(1b) x jgroup(2b, 128 j each) x i(9b).
// Wave w owns j-rows [jg*128 + w*32, +32) as 2 16-row tiles.
// LDS: 40 KB occupancy ballast (never touched at runtime).
// ---------------------------------------------------------------------------
static __device__ inline f16x8 relu_sub8(f16x8 a, f16x8 b) {
  f16x8 d = a - b;
  const f16x8 z = {};
  return __builtin_elementwise_max(d, z);
}

__global__ __launch_bounds__(256)
void edge_kernel(
    const half_t* __restrict__ gh, const half_t* __restrict__ gbh,
    const half_t* __restrict__ W2T, const half_t* __restrict__ W3T,
    const float* __restrict__ bc2, const float* __restrict__ bc3,
    const float* __restrict__ Wo, const float* __restrict__ bo,
    float* __restrict__ out)
{
  // Occupancy ballast: 40 KB -> 4 blocks/CU -> allocator budget 128 VGPRs.
  // Guard depends on runtime data (bo) so the allocation can't be eliminated;
  // branch is uniform and never taken for real inputs.
  __shared__ half_t occ_pad[20480];

  const int t = threadIdx.x, lane = t & 63, w = t >> 6;
  const int c = lane & 15, q = lane >> 4;
  const int bid = blockIdx.x;
  const int b = bid >> 11, jg = (bid >> 9) & 3, i = bid & 511;
  const int j0w = jg * 128 + w * 32;
  const float bo0 = bo[0];
  const int rdoff = lane * 8;

  // ---- phase A: e1[ks][jt] in regs (32 VGPRs) ----
  f16x8 e1[4][2];
  {
    f16x8 gih[4];
    #pragma unroll
    for (int ks = 0; ks < 4; ks++)
      gih[ks] = *(const f16x8*)(gh + (size_t)(b * 512 + i) * 128 + ks * 32 + q * 8);
    #pragma unroll
    for (int ks = 0; ks < 4; ks++)
      #pragma unroll
      for (int jt = 0; jt < 2; jt++) {
        const f16x8 gj = *(const f16x8*)(gbh + (size_t)(b * 512 + j0w + jt * 16 + c) * 128 + ks * 32 + q * 8);
        e1[ks][jt] = relu_sub8(gj, gih[ks]);
      }
  }

  // ---- phase B: layer 2 (16x16x32); pk[nt][jt] = relu(acc2+bc2) packed
  //      f16x4 — identical bits to the layer-3 16x16x16 B-fragment ----
  f16x4 pk[8][2];
  #pragma unroll 1
  for (int nt = 0; nt < 8; nt++) {
    f32x4 acc[2] = {};
    #pragma unroll 1
    for (int ks = 0; ks < 4; ks++) {
      const f16x8 wf = *(const f16x8*)(W2T + (ks * 8 + nt) * 512 + rdoff);
      #pragma unroll
      for (int jt = 0; jt < 2; jt++)
        acc[jt] = __builtin_amdgcn_mfma_f32_16x16x32_f16(wf, e1[ks][jt], acc[jt], 0, 0, 0);
    }
    const f32x4 b2 = *(const f32x4*)(bc2 + nt * 16 + q * 4);
    #pragma unroll
    for (int jt = 0; jt < 2; jt++) {
      f16x4 pv;
      pv[0] = (half_t)fmaxf(acc[jt][0] + b2[0], 0.f);
      pv[1] = (half_t)fmaxf(acc[jt][1] + b2[1], 0.f);
      pv[2] = (half_t)fmaxf(acc[jt][2] + b2[2], 0.f);
      pv[3] = (half_t)fmaxf(acc[jt][3] + b2[3], 0.f);
      pk[nt][jt] = pv;
    }
  }

  // ---- phase C: layer 3 (16x16x16, kc = layer-2 nt), epilogue fused;
  //      weights loaded b128 as kc-pairs ----
  float p[2] = {0.f, 0.f};
  #pragma unroll 1
  for (int nt3 = 0; nt3 < 8; nt3++) {
    f32x4 acc[2] = {};
    #pragma unroll 1
    for (int kp = 0; kp < 4; kp++) {
      const f16x8 wf8 = *(const f16x8*)(W3T + (kp * 8 + nt3) * 512 + rdoff);
      const f16x4 w0 = __builtin_shufflevector(wf8, wf8, 0, 1, 2, 3);
      const f16x4 w1 = __builtin_shufflevector(wf8, wf8, 4, 5, 6, 7);
      #pragma unroll
      for (int jt = 0; jt < 2; jt++) {
        acc[jt] = __builtin_amdgcn_mfma_f32_16x16x16f16(w0, pk[2 * kp + 0][jt], acc[jt], 0, 0, 0);
        acc[jt] = __builtin_amdgcn_mfma_f32_16x16x16f16(w1, pk[2 * kp + 1][jt], acc[jt], 0, 0, 0);
      }
    }
    const f32x4 b3 = *(const f32x4*)(bc3 + nt3 * 16 + q * 4);
    const f32x4 wo = *(const f32x4*)(Wo  + nt3 * 16 + q * 4);
    #pragma unroll
    for (int jt = 0; jt < 2; jt++)
      #pragma unroll
      for (int r = 0; r < 4; r++)
        p[jt] = fmaf(fmaxf(acc[jt][r] + b3[r], 0.f), wo[r], p[jt]);
  }

  // ---- keep occ_pad alive (runtime-unprovable, never taken) ----
  if (bo0 == 1234567.0f) {
    occ_pad[t] = (half_t)p[0];
    p[1] += (float)occ_pad[(t * 7) & 20479];
  }

  // ---- reduce over q (n3 rows split across q), store ----
  #pragma unroll
  for (int jt = 0; jt < 2; jt++) {
    p[jt] += __shfl_xor(p[jt], 16, 64);
    p[jt] += __shfl_xor(p[jt], 32, 64);
  }
  if (q == 0) {
    const size_t base = ((size_t)(b * 512 + i)) * 512 + j0w;
    out[base + c]      = p[0] + bo0;
    out[base + 16 + c] = p[1] + bo0;
  }
}

// ---------------------------------------------------------------------------
extern "C" void kernel_launch(void* const* d_in, const int* in_sizes, int n_in,
                              void* d_out, int out_size, void* d_ws, size_t ws_size,
                              hipStream_t stream)
{
  const float* x   = (const float*)d_in[0];
  const float* Wa  = (const float*)d_in[1];
  const float* ba  = (const float*)d_in[2];
  const float* Wb  = (const float*)d_in[3];
  const float* bb  = (const float*)d_in[4];
  const float* Wc1 = (const float*)d_in[5];
  const float* bc1 = (const float*)d_in[6];
  const float* Wc2 = (const float*)d_in[7];
  const float* bc2 = (const float*)d_in[8];
  const float* Wc3 = (const float*)d_in[9];
  const float* bc3 = (const float*)d_in[10];
  const float* Wo  = (const float*)d_in[11];
  const float* bo  = (const float*)d_in[12];
  float* out = (float*)d_out;

  char* ws = (char*)d_ws;
  half_t* gh  = (half_t*)ws;                      // 256 KB
  half_t* gbh = (half_t*)(ws + 262144);           // 256 KB
  half_t* W2T = (half_t*)(ws + 524288);           // 32 KB
  half_t* W3T = (half_t*)(ws + 557056);           // 32 KB

  prep_kernel<<<272, 256, 0, stream>>>(x, Wa, ba, Wb, bb, Wc1, bc1, Wc2, Wc3,
                                       gh, gbh, W2T, W3T);
  edge_kernel<<<4096, 256, 0, stream>>>(gh, gbh, W2T, W3T, bc2, bc3, Wo, bo, out);
}